// Round 13
// baseline (1399.622 us; speedup 1.0000x reference)
//
#include <hip/hip_runtime.h>
#include <math.h>

#define HIDDEN 100
#define HEADS 8
#define D 800          // HIDDEN*HEADS
#define ALPHA 0.2f

typedef unsigned short ushort;
typedef unsigned int uint;
typedef __attribute__((ext_vector_type(8))) _Float16 f16x8;
typedef __attribute__((ext_vector_type(4))) float f32x4;

__device__ inline float h2f(ushort u) { union { ushort s; _Float16 h; } v; v.s = u; return (float)v.h; }
__device__ inline ushort f2h(float f) { union { ushort s; _Float16 h; } v; v.h = (_Float16)f; return v.s; }

// async global->LDS, 16B per lane; LDS dest must be the WAVE-UNIFORM base (HW adds lane*16)
__device__ inline void gl_lds16(const void* g, void* l) {
    __builtin_amdgcn_global_load_lds((const __attribute__((address_space(1))) void*)g,
                                     (__attribute__((address_space(3))) void*)l, 16, 0, 0);
}

// ---------- CSR row_ptr from sorted src via binary search ----------
__global__ void k_rowptr(const int* __restrict__ src, int E, int n, int* __restrict__ row_ptr) {
    int i = blockIdx.x * blockDim.x + threadIdx.x;
    if (i > n) return;
    int lo = 0, hi = E;
    while (lo < hi) { int mid = (lo + hi) >> 1; if (src[mid] < i) lo = mid + 1; else hi = mid; }
    row_ptr[i] = lo;
}

// ---------- repack kernels (3,8,800,100) -> per-layer transposed f16 ----------
// Bsp layout: [layer][n=800][k=800] f16, Bt[n][k] = kin[l, n/100, k, n%100]
__global__ void k_repack(const float* __restrict__ kin, ushort* __restrict__ bsp) {
    int gid = blockIdx.x * blockDim.x + threadIdx.x;
    if (gid >= 3 * D * D) return;
    int l = gid / (D * D);
    int rem = gid % (D * D);
    int nn = rem / D;        // output col (n)
    int k = rem % D;         // output row in k
    int h = nn / HIDDEN, c = nn % HIDDEN;
    float v = kin[((size_t)(l * HEADS + h) * D + k) * HIDDEN + c];
    bsp[((size_t)l * D + nn) * D + k] = f2h(v);
}

// ---------- x = relu(ns @ W_pre + b_pre), K=32; output single f16 plane ----------
__global__ __launch_bounds__(256) void k_pre(const float* __restrict__ ns, const float* __restrict__ W,
                                             const float* __restrict__ b, ushort* __restrict__ xf, int n) {
    int j = blockIdx.x * 256 + threadIdx.x;
    if (j >= D) return;
    float wk[32];
#pragma unroll
    for (int k = 0; k < 32; k++) wk[k] = W[k * D + j];
    float bj = b[j];
    int r0 = blockIdx.y * 32;
    int r1 = min(r0 + 32, n);
    for (int r = r0; r < r1; r++) {
        float acc = bj;
#pragma unroll
        for (int k = 0; k < 32; k++) acc += ns[r * 32 + k] * wk[k];
        xf[(size_t)r * D + j] = f2h(fmaxf(acc, 0.f));
    }
}

// ---------- Ht[M x 800](f16) = xf @ Bsp, single-pass f16 MFMA + FUSED s/t epilogue ----------
// BM=128 BN=160 BK=32; 4 waves (2x2); dbuf LDS 36KB; global_load_lds staging;
// counted-vmcnt pipeline; XCD-aware block swizzle. Epilogue: one (mi,rr) at a time
// (4 live partials), 16-lane shfl reduce, atomicAdd into zeroed s_all/t_all.
__global__ __launch_bounds__(256) void k_gemm(const ushort* __restrict__ xf, const ushort* __restrict__ Bsp,
                                              const float* __restrict__ att_l, ushort* __restrict__ C,
                                              float* __restrict__ s_all, float* __restrict__ t_all, int M) {
    // single fragment-ordered LDS: tiles 0..7 = A (rows), 8..17 = B (cols); 1KB per 16x32 tile
    __shared__ __align__(16) ushort Sf[2][18 * 512];   // 36 KB

    int d = blockIdx.x;
    int q = d & 7, m = d >> 3;      // XCD swizzle: same row-block -> same XCD
    int c = m % 5, j = m / 5;
    int r = j * 8 + q;
    int nrb = (M + 127) >> 7;
    if (r >= nrb) return;
    int row0 = r * 128, col0 = c * 160;

    int t = threadIdx.x;
    int w = t >> 6, lane = t & 63;
    int wr = w >> 1, wc = w & 1;
    int l15 = lane & 15, ks = lane >> 4;

    // 18 loads: idx 0..7 A-tiles, 8..17 B-tiles; wave w handles idx%4==w -> cnt {5,5,4,4}
    int cnt = (w < 2) ? 5 : 4;
    const ushort* srcs[5];
    uint ldso[5];
    {
        int c2 = 0;
        for (int idx = w; idx < 18; idx += 4, c2++) {
            if (idx < 8) {
                int row = min(row0 + idx * 16 + l15, M - 1);
                srcs[c2] = xf + (size_t)row * D + ks * 8;
            } else {
                int col = col0 + (idx - 8) * 16 + l15;
                srcs[c2] = Bsp + (size_t)col * D + ks * 8;
            }
            ldso[c2] = idx * 512;
        }
    }

    f32x4 acc[4][5] = {};

    auto stage = [&](int buf, int k0) {
        for (int i = 0; i < cnt; i++) gl_lds16(srcs[i] + k0, &Sf[buf][ldso[i]]);
    };
    auto compute = [&](int buf) {
        f16x8 bh[5];
#pragma unroll
        for (int ni = 0; ni < 5; ni++)
            bh[ni] = *(const f16x8*)&Sf[buf][(8 + wc * 5 + ni) * 512 + lane * 8];
#pragma unroll
        for (int mi = 0; mi < 4; mi++) {
            f16x8 ah = *(const f16x8*)&Sf[buf][(wr * 4 + mi) * 512 + lane * 8];
#pragma unroll
            for (int ni = 0; ni < 5; ni++)
                acc[mi][ni] = __builtin_amdgcn_mfma_f32_16x16x32_f16(ah, bh[ni], acc[mi][ni], 0, 0, 0);
        }
    };

    stage(0, 0);                               // S_0 in flight
    for (int kt = 0; kt < 25; kt++) {
        if (kt < 24) {
            stage((kt + 1) & 1, (kt + 1) * 32);   // S_{t+1} stays in flight across the barrier
            if (w < 2) asm volatile("s_waitcnt vmcnt(5)" ::: "memory");
            else       asm volatile("s_waitcnt vmcnt(4)" ::: "memory");
        } else {
            asm volatile("s_waitcnt vmcnt(0)" ::: "memory");
        }
        __builtin_amdgcn_s_barrier();          // all waves' S_t landed (raw barrier, no drain)
        compute(kt & 1);
        __builtin_amdgcn_s_barrier();          // all waves done reading buf before re-stage
    }

    // C/D layout: col = lane&15, row = (lane>>4)*4 + reg   [m89-verified]
#pragma unroll
    for (int mi = 0; mi < 4; mi++) {
#pragma unroll
        for (int ni = 0; ni < 5; ni++) {
            int gr0 = row0 + wr * 64 + mi * 16 + ks * 4;
            int gc = col0 + wc * 80 + ni * 16 + l15;
#pragma unroll
            for (int rr = 0; rr < 4; rr++) {
                int gr = gr0 + rr;
                if (gr < M) C[(size_t)gr * D + gc] = f2h(acc[mi][ni][rr]);
            }
        }
    }

    // ---- fused s/t epilogue: wave cols W0..W0+79 span <= 2 heads; one (mi,rr) at a time ----
    int W0 = col0 + wc * 80;
    int hb = W0 / 100;
    bool span = (W0 % 100) > 20;
    float as_[5], at_[5];
    int idx_[5];
#pragma unroll
    for (int ni = 0; ni < 5; ni++) {
        int gc = W0 + ni * 16 + l15;
        int hd = gc / 100, cc = gc - hd * 100;
        as_[ni] = att_l[hd * 200 + cc];
        at_[ni] = att_l[hd * 200 + 100 + cc];
        idx_[ni] = hd - hb;                    // 0 or 1
    }
#pragma unroll
    for (int mi = 0; mi < 4; mi++) {
#pragma unroll
        for (int rr = 0; rr < 4; rr++) {
            float p0 = 0.f, p1 = 0.f, q0 = 0.f, q1 = 0.f;
#pragma unroll
            for (int ni = 0; ni < 5; ni++) {
                float v = acc[mi][ni][rr];
                if (idx_[ni] == 0) { p0 += v * as_[ni]; q0 += v * at_[ni]; }
                else               { p1 += v * as_[ni]; q1 += v * at_[ni]; }
            }
#pragma unroll
            for (int o = 1; o < 16; o <<= 1) {
                p0 += __shfl_xor(p0, o); q0 += __shfl_xor(q0, o);
                p1 += __shfl_xor(p1, o); q1 += __shfl_xor(q1, o);
            }
            if (l15 == 0) {
                int gr = row0 + wr * 64 + mi * 16 + ks * 4 + rr;
                if (gr < M) {
                    atomicAdd(&s_all[gr * 8 + hb], p0);
                    atomicAdd(&t_all[gr * 8 + hb], q0);
                    if (span) {
                        atomicAdd(&s_all[gr * 8 + hb + 1], p1);
                        atomicAdd(&t_all[gr * 8 + hb + 1], q1);
                    }
                }
            }
        }
    }
}

// ---------- per-node segment softmax + aggregate + relu + residual (x f16 in-place) ----------
__global__ __launch_bounds__(256) void k_edge(const ushort* __restrict__ Ht, ushort* __restrict__ xf,
                                              const float* __restrict__ s_all, const float* __restrict__ t_all,
                                              const int* __restrict__ dst, const int* __restrict__ row_ptr,
                                              int n) {
    int i = blockIdx.x;
    int t = threadIdx.x;
    __shared__ float lw[32][8];
    __shared__ int ld[32];
    int e0 = row_ptr[i], e1 = row_ptr[i + 1];
    int h = t / 25;            // head for aggregation (valid for t<200)
    int el = t >> 3, hh = t & 7;
    float s_ih = s_all[i * 8 + hh];
    float acc0 = 0, acc1 = 0, acc2 = 0, acc3 = 0, den = 0;

    for (int base = e0; base < e1; base += 32) {
        int cnt = min(32, e1 - base);
        __syncthreads();
        if (el < cnt) {
            int dd = dst[base + el];
            float ev = s_ih + t_all[dd * 8 + hh];
            ev = ev >= 0.f ? ev : ALPHA * ev;
            ev = fminf(fmaxf(ev, -2.f), 2.f);
            lw[el][hh] = __expf(ev);
            if (hh == 0) ld[el] = dd;
        }
        __syncthreads();
        if (t < 200) {
#pragma unroll 4
            for (int e = 0; e < cnt; e++) {
                int dd = ld[e];
                uint2 v = *(const uint2*)(Ht + (size_t)dd * D + t * 4);
                float wgt = lw[e][h];
                acc0 += wgt * h2f((ushort)(v.x & 0xFFFF));
                acc1 += wgt * h2f((ushort)(v.x >> 16));
                acc2 += wgt * h2f((ushort)(v.y & 0xFFFF));
                acc3 += wgt * h2f((ushort)(v.y >> 16));
                den += wgt;
            }
        }
    }
    if (t < 200) {
        size_t off = (size_t)i * D + t * 4;
        uint2 vx = *(uint2*)(xf + off);
        float x0 = h2f((ushort)(vx.x & 0xFFFF));
        float x1 = h2f((ushort)(vx.x >> 16));
        float x2 = h2f((ushort)(vx.y & 0xFFFF));
        float x3 = h2f((ushort)(vx.y >> 16));
        float inv = den > 0.f ? 1.f / den : 0.f;
        x0 += fmaxf(acc0 * inv, 0.f);
        x1 += fmaxf(acc1 * inv, 0.f);
        x2 += fmaxf(acc2 * inv, 0.f);
        x3 += fmaxf(acc3 * inv, 0.f);
        *(uint2*)(xf + off) = make_uint2((uint)f2h(x0) | ((uint)f2h(x1) << 16),
                                         (uint)f2h(x2) | ((uint)f2h(x3) << 16));
    }
}

// ---------- final stage A: per-block partial of sum_i (x_i . Wl + bl) * Wc_i ----------
__global__ __launch_bounds__(256) void k_final(const ushort* __restrict__ xf, const float* __restrict__ Wl,
                                               const float* __restrict__ bl, const float* __restrict__ Wc,
                                               float* __restrict__ fpart, int n) {
    __shared__ float part[4];
    int lane = threadIdx.x & 63, w = threadIdx.x >> 6;
    int wid = blockIdx.x * 4 + w;
    int nw = gridDim.x * 4;
    float p = 0.f;
    for (int i = wid; i < n; i += nw) {
        float dot = 0.f;
#pragma unroll
        for (int r = 0; r < 13; r++) {
            int j = r * 64 + lane;
            if (j < D) dot += h2f(xf[(size_t)i * D + j]) * Wl[j];
        }
#pragma unroll
        for (int off = 32; off; off >>= 1) dot += __shfl_xor(dot, off);
        if (lane == 0) p += (dot + bl[0]) * Wc[i];
    }
    if (lane == 0) part[w] = p;
    __syncthreads();
    if (threadIdx.x == 0) fpart[blockIdx.x] = part[0] + part[1] + part[2] + part[3];
}

// ---------- final stage B ----------
__global__ __launch_bounds__(64) void k_reduce(const float* __restrict__ fpart, const float* __restrict__ bc,
                                               float* __restrict__ out, int nb) {
    if (threadIdx.x == 0) {
        float s = 0.f;
        for (int q = 0; q < nb; q++) s += fpart[q];
        out[0] = s + bc[0];
    }
}

// ---------- sentinel if workspace too small ----------
__global__ void k_sentinel(float* out) { out[0] = 12345.0f; }

extern "C" void kernel_launch(void* const* d_in, const int* in_sizes, int n_in,
                              void* d_out, int out_size, void* d_ws, size_t ws_size,
                              hipStream_t stream) {
    const float* ns   = (const float*)d_in[0];
    const int*   src  = (const int*)d_in[1];
    const int*   dst  = (const int*)d_in[2];
    const float* Wpre = (const float*)d_in[3];
    const float* bpre = (const float*)d_in[4];
    const float* kern = (const float*)d_in[5];
    const float* att  = (const float*)d_in[6];
    const float* Wl   = (const float*)d_in[7];
    const float* bl   = (const float*)d_in[8];
    const float* Wc   = (const float*)d_in[9];
    const float* bc   = (const float*)d_in[10];
    int n = in_sizes[9];   // Wc has n elements
    int E = in_sizes[1];

    size_t need = 0;
    auto sz = [&](size_t bytes) { size_t o = need; need += (bytes + 255) & ~255ull; return o; };
    size_t o_xf    = sz((size_t)n * D * 2);          // f16 x plane (in-place across layers)
    size_t o_Ht    = sz((size_t)n * D * 2);          // f16 Ht
    size_t o_bsp   = sz(3ull * D * D * 2);           // f16 transposed weights
    size_t o_s     = sz((size_t)n * 8 * 4);
    size_t o_t     = sz((size_t)n * 8 * 4);
    size_t o_rp    = sz(((size_t)n + 1) * 4);
    size_t o_fp    = sz(128 * 4);

    if (need > ws_size) {   // diagnostic: absmax will be ~12345
        k_sentinel<<<1, 1, 0, stream>>>((float*)d_out);
        return;
    }

    char* ws = (char*)d_ws;
    ushort* xf    = (ushort*)(ws + o_xf);
    ushort* Ht    = (ushort*)(ws + o_Ht);
    ushort* bsp   = (ushort*)(ws + o_bsp);
    float*  s_all = (float*)(ws + o_s);
    float*  t_all = (float*)(ws + o_t);
    int*    row_ptr = (int*)(ws + o_rp);
    float*  fpart = (float*)(ws + o_fp);

    k_rowptr<<<(n + 1 + 255) / 256, 256, 0, stream>>>(src, E, n, row_ptr);
    k_repack<<<(3 * D * D + 255) / 256, 256, 0, stream>>>(kern, bsp);
    dim3 gpre((D + 255) / 256, (n + 31) / 32);
    k_pre<<<gpre, 256, 0, stream>>>(ns, Wpre, bpre, xf, n);

    int nrb = (n + 127) / 128;                    // 391 row blocks
    int grid_g = 8 * (((nrb + 7) / 8) * 5);       // swizzle-decoded inside kernel
    for (int l = 0; l < 3; l++) {
        hipMemsetAsync(s_all, 0, (size_t)n * 8 * 4, stream);
        hipMemsetAsync(t_all, 0, (size_t)n * 8 * 4, stream);
        k_gemm<<<grid_g, 256, 0, stream>>>(xf, bsp + (size_t)l * D * D,
                                           att + l * HEADS * 2 * HIDDEN, Ht, s_all, t_all, n);
        k_edge<<<n, 256, 0, stream>>>(Ht, xf, s_all, t_all, dst, row_ptr, n);
    }

    k_final<<<120, 256, 0, stream>>>(xf, Wl, bl, Wc, fpart, n);
    k_reduce<<<1, 64, 0, stream>>>(fpart, bc, (float*)d_out, 120);
}